// Round 6
// baseline (198.238 us; speedup 1.0000x reference)
//
#include <hip/hip_runtime.h>

// Tuples (k=2): x (B=4, n=512, f=128) f32 -> out (B, n*n, 2f)
// out[b, i*n+j, c] = (c < f) ? x[b,i,c] : x[b,j,c-f]
//
// R6: pure-store inner loop. All source values hoisted to registers
// (vi[8] from L2-resident global, vj[8] from one-time LDS reads), so the
// 64-store loop has NO loads, NO waitcnt, and each wave writes sequential
// 1 KB steps (k-inner walks 8 consecutive output rows). Matches the
// fill kernel's store-only structure as closely as possible.

#define BATCH 4
#define NROW  512

typedef float f32x4 __attribute__((ext_vector_type(4)));

__global__ void __launch_bounds__(256) tuples_reg_kernel(
    const f32x4* __restrict__ x, f32x4* __restrict__ out)
{
    __shared__ f32x4 lds_j[32 * 32];          // 16 KB: 32 j-rows

    const unsigned bid = blockIdx.x;          // 4096 blocks
    const unsigned jb  = bid & 15u;           // j-block (32 rows)
    const unsigned ib  = (bid >> 4) & 63u;    // i-block (8 rows)
    const unsigned b   = bid >> 10;           // batch
    const unsigned t   = threadIdx.x;         // 256 threads

    // ---- stage 32 j-rows (1024 f32x4 = 16 KB) ----
    const f32x4* srcj = x + (b << 14) + (jb << 10);
    #pragma unroll
    for (int q = 0; q < 4; ++q)
        lds_j[t + ((unsigned)q << 8)] = srcj[t + ((unsigned)q << 8)];

    const unsigned c4 = t & 63u;              // output f32x4 slot
    const unsigned r0 = t >> 6;               // wave id (0..3)
    const unsigned cs = c4 & 31u;             // source column slot
    const bool ihalf  = (c4 < 32u);

    // ---- i-rows straight from global (L2-resident, broadcast-coalesced) ----
    f32x4 vi[8];
    #pragma unroll
    for (int il = 0; il < 8; ++il)
        vi[il] = x[(b << 14) + (((ib << 3) | (unsigned)il) << 5) + cs];

    __syncthreads();

    // ---- this wave's 8 j-rows -> registers (conflict-free ds_read_b128) ----
    f32x4 vj[8];
    #pragma unroll
    for (int k = 0; k < 8; ++k)
        vj[k] = lds_j[(((r0 << 3) | (unsigned)k) << 5) | cs];

    // out f32x4 index = (b<<24)|(i<<15)|(j<<6)|c4, i=(ib<<3)|il, j=(jb<<5)|(r0<<3)|k
    f32x4* o = out + ((size_t)b << 24) + ((size_t)ib << 18)
                   + ((size_t)jb << 11) + ((size_t)r0 << 9) + c4;

    // ---- 64 pure stores; k-inner = 8 sequential 1 KB wave-steps ----
    #pragma unroll
    for (int il = 0; il < 8; ++il) {
        const f32x4 a = vi[il];
        f32x4* oi = o + ((size_t)il << 15);
        #pragma unroll
        for (int k = 0; k < 8; ++k) {
            f32x4 v = ihalf ? a : vj[k];
            oi[(size_t)k << 6] = v;
        }
    }
}

extern "C" void kernel_launch(void* const* d_in, const int* in_sizes, int n_in,
                              void* d_out, int out_size, void* d_ws, size_t ws_size,
                              hipStream_t stream)
{
    const f32x4* x = (const f32x4*)d_in[0];
    f32x4* out = (f32x4*)d_out;
    tuples_reg_kernel<<<BATCH * (NROW / 8) * (NROW / 32), 256, 0, stream>>>(x, out);
}